// Round 1
// baseline (2142.355 us; speedup 1.0000x reference)
//
#include <hip/hip_runtime.h>

#define NN 100000
#define NE 3200000
#define HD 64
#define RD 500

// ---------------- layer 1 edge kernel: F=2 messages, thread per edge ---------
__global__ __launch_bounds__(256) void edge1_kernel(
    const float* __restrict__ x, const float* __restrict__ ea,
    const int* __restrict__ src, const int* __restrict__ dst,
    const float* __restrict__ elw, const float* __restrict__ elb,
    float* __restrict__ agg) {
  float w0[7], w1[7];
#pragma unroll
  for (int k = 0; k < 7; k++) { w0[k] = elw[k * 2]; w1[k] = elw[k * 2 + 1]; }
  float b0 = elb[0], b1 = elb[1];
  int stride = gridDim.x * 256;
  for (int e = blockIdx.x * 256 + threadIdx.x; e < NE; e += stride) {
    int s = src[e], d = dst[e];
    float m0 = b0, m1 = b1;
#pragma unroll
    for (int k = 0; k < 7; k++) {
      float a = ea[e * 7 + k];
      m0 = fmaf(a, w0[k], m0);
      m1 = fmaf(a, w1[k], m1);
    }
    m0 = fmaxf(m0 + x[s * 2 + 0], 0.f);
    m1 = fmaxf(m1 + x[s * 2 + 1], 0.f);
    unsafeAtomicAdd(&agg[d * 2 + 0], m0);
    unsafeAtomicAdd(&agg[d * 2 + 1], m1);
  }
}

// ---------------- layers 2/3 edge kernel: wave per edge, lane = channel ------
__global__ __launch_bounds__(256) void edge64_kernel(
    const float* __restrict__ xin, const float* __restrict__ ea,
    const int* __restrict__ src, const int* __restrict__ dst,
    const float* __restrict__ elw, const float* __restrict__ elb,
    float* __restrict__ agg) {
  int lane = threadIdx.x & 63;
  int wid = (blockIdx.x * 256 + threadIdx.x) >> 6;
  int nw = (gridDim.x * 256) >> 6;
  float w[7];
#pragma unroll
  for (int k = 0; k < 7; k++) w[k] = elw[k * 64 + lane];
  float b = elb[lane];
  for (int e = wid; e < NE; e += nw) {
    int eu = __builtin_amdgcn_readfirstlane(e);
    int s = src[eu];
    int d = dst[eu];
    float m = b;
#pragma unroll
    for (int k = 0; k < 7; k++) m = fmaf(ea[eu * 7 + k], w[k], m);
    m += xin[s * 64 + lane];
    m = fmaxf(m, 0.f);
    unsafeAtomicAdd(&agg[d * 64 + lane], m);
  }
}

// ------------- layer1 node A: h=(1+eps)x+agg [N,2]; t = h@w1[2,64]+b1; stats -
__global__ __launch_bounds__(256) void nodeA2_kernel(
    const float* __restrict__ x, const float* __restrict__ agg1,
    float* __restrict__ tbuf, const float* __restrict__ w1,
    const float* __restrict__ b1, const float* __restrict__ eps_p,
    float* __restrict__ stats) {
  __shared__ float red[256];
  int tid = threadIdx.x;
  int c = tid & 63, nl = tid >> 6;
  float wa = w1[c], wb = w1[64 + c], bc = b1[c];
  float ep = 1.0f + *eps_p;
  float s = 0.f, ss = 0.f;
  for (int n0 = blockIdx.x * 4; n0 < NN; n0 += gridDim.x * 4) {
    int n = n0 + nl;
    if (n < NN) {
      float h0 = ep * x[n * 2 + 0] + agg1[n * 2 + 0];
      float h1 = ep * x[n * 2 + 1] + agg1[n * 2 + 1];
      float t = fmaf(h1, wb, fmaf(h0, wa, bc));
      tbuf[n * 64 + c] = t;
      s += t;
      ss += t * t;
    }
  }
  double* dsum = (double*)stats;
  red[tid] = s;
  __syncthreads();
  if (tid < 64) unsafeAtomicAdd(&dsum[tid], (double)(red[tid] + red[tid + 64] + red[tid + 128] + red[tid + 192]));
  __syncthreads();
  red[tid] = ss;
  __syncthreads();
  if (tid < 64) unsafeAtomicAdd(&dsum[64 + tid], (double)(red[tid] + red[tid + 64] + red[tid + 128] + red[tid + 192]));
}

// ------------- layers 2/3 node A: h=(1+eps)x+agg; t = h@w1[64,64]+b1; stats --
__global__ __launch_bounds__(256) void nodeA64_kernel(
    const float* __restrict__ xin, float* __restrict__ tbuf /* agg in, t out */,
    const float* __restrict__ w1, const float* __restrict__ b1,
    const float* __restrict__ eps_p, float* __restrict__ stats) {
  __shared__ float wl[64 * 64];
  __shared__ float hbuf[4][64];
  __shared__ float red[256];
  int tid = threadIdx.x;
  int c = tid & 63, nl = tid >> 6;
  for (int i = tid; i < 64 * 64; i += 256) wl[i] = w1[i];
  float ep = 1.0f + *eps_p;
  float bc = b1[c];
  float s = 0.f, ss = 0.f;
  __syncthreads();
  for (int n0 = blockIdx.x * 4; n0 < NN; n0 += gridDim.x * 4) {
    int n = n0 + nl;
    bool valid = n < NN;
    float h = 0.f;
    if (valid) h = ep * xin[n * 64 + c] + tbuf[n * 64 + c];
    hbuf[nl][c] = h;
    __syncthreads();
    if (valid) {
      float t = bc;
#pragma unroll
      for (int k = 0; k < 64; k++) t = fmaf(hbuf[nl][k], wl[k * 64 + c], t);
      tbuf[n * 64 + c] = t;
      s += t;
      ss += t * t;
    }
    __syncthreads();
  }
  double* dsum = (double*)stats;
  red[tid] = s;
  __syncthreads();
  if (tid < 64) unsafeAtomicAdd(&dsum[tid], (double)(red[tid] + red[tid + 64] + red[tid + 128] + red[tid + 192]));
  __syncthreads();
  red[tid] = ss;
  __syncthreads();
  if (tid < 64) unsafeAtomicAdd(&dsum[64 + tid], (double)(red[tid] + red[tid + 64] + red[tid + 128] + red[tid + 192]));
}

// ------------- BN stats finalize: scale/shift ---------------------------------
__global__ void statsfin_kernel(float* stats, const float* __restrict__ g,
                                const float* __restrict__ bt) {
  int c = threadIdx.x;  // 64 threads
  const double* ds = (const double*)stats;
  double m = ds[c] / (double)NN;
  double v = ds[64 + c] / (double)NN - m * m;
  float sc = g[c] * (float)(1.0 / sqrt(v + 1e-5));
  stats[256 + c] = sc;
  stats[320 + c] = bt[c] - (float)m * sc;
}

// ------------- node B: u=relu(BN(t)); out=relu(u@w2+b2) (may be in-place) ----
__global__ __launch_bounds__(256) void nodeB_kernel(
    const float* __restrict__ tin, float* __restrict__ outb,
    const float* __restrict__ w2, const float* __restrict__ b2,
    const float* __restrict__ stats) {
  __shared__ float wl[64 * 64];
  __shared__ float ubuf[4][64];
  int tid = threadIdx.x;
  int c = tid & 63, nl = tid >> 6;
  for (int i = tid; i < 64 * 64; i += 256) wl[i] = w2[i];
  float scale = stats[256 + c], shift = stats[320 + c], bc = b2[c];
  __syncthreads();
  for (int n0 = blockIdx.x * 4; n0 < NN; n0 += gridDim.x * 4) {
    int n = n0 + nl;
    bool valid = n < NN;
    float u = 0.f;
    if (valid) {
      float t = tin[n * 64 + c];
      u = fmaxf(fmaf(t, scale, shift), 0.f);
    }
    ubuf[nl][c] = u;
    __syncthreads();
    if (valid) {
      float o = bc;
#pragma unroll
      for (int k = 0; k < 64; k++) o = fmaf(ubuf[nl][k], wl[k * 64 + c], o);
      outb[n * 64 + c] = fmaxf(o, 0.f);
    }
    __syncthreads();
  }
}

// ------------- head: y = leaky(out@reg_w + reg_b) @ end_w + end_b ------------
__global__ __launch_bounds__(256) void final_kernel(
    const float* __restrict__ xin, const float* __restrict__ regw,
    const float* __restrict__ regb, const float* __restrict__ endw,
    const float* __restrict__ endb, float* __restrict__ out) {
  __shared__ float wl[64 * 128];  // [k][jl], chunk of 125 j's padded to 128
  __shared__ float eb[256];       // [0..124]=reg_b chunk, [128..252]=end_w chunk
  int tid = threadIdx.x;
  int node = blockIdx.x * 256 + tid;
  bool valid = node < NN;
  float xr[64];
  if (valid) {
    const float4* xp = (const float4*)(xin + node * 64);
#pragma unroll
    for (int k4 = 0; k4 < 16; k4++) {
      float4 v = xp[k4];
      xr[k4 * 4 + 0] = v.x; xr[k4 * 4 + 1] = v.y;
      xr[k4 * 4 + 2] = v.z; xr[k4 * 4 + 3] = v.w;
    }
  }
  float y = 0.f;
  for (int ch = 0; ch < 4; ch++) {
    int j0 = ch * 125;
    __syncthreads();
    for (int idx = tid; idx < 64 * 125; idx += 256) {
      int k = idx / 125;
      int jl = idx - k * 125;
      wl[k * 128 + jl] = regw[k * 500 + j0 + jl];
    }
    if (tid < 125) { eb[tid] = regb[j0 + tid]; eb[128 + tid] = endw[j0 + tid]; }
    __syncthreads();
    if (valid) {
      int jl = 0;
      for (; jl + 4 <= 125; jl += 4) {
        float t0 = eb[jl], t1 = eb[jl + 1], t2 = eb[jl + 2], t3 = eb[jl + 3];
#pragma unroll
        for (int k = 0; k < 64; k++) {
          float4 w4 = *(const float4*)&wl[k * 128 + jl];
          float xv = xr[k];
          t0 = fmaf(xv, w4.x, t0);
          t1 = fmaf(xv, w4.y, t1);
          t2 = fmaf(xv, w4.z, t2);
          t3 = fmaf(xv, w4.w, t3);
        }
        t0 = t0 >= 0.f ? t0 : 0.01f * t0;
        t1 = t1 >= 0.f ? t1 : 0.01f * t1;
        t2 = t2 >= 0.f ? t2 : 0.01f * t2;
        t3 = t3 >= 0.f ? t3 : 0.01f * t3;
        y += t0 * eb[128 + jl] + t1 * eb[128 + jl + 1] + t2 * eb[128 + jl + 2] + t3 * eb[128 + jl + 3];
      }
      {  // tail jl = 124
        float t = eb[124];
#pragma unroll
        for (int k = 0; k < 64; k++) t = fmaf(xr[k], wl[k * 128 + 124], t);
        t = t >= 0.f ? t : 0.01f * t;
        y += t * eb[128 + 124];
      }
    }
  }
  if (valid) out[node] = y + endb[0];
}

extern "C" void kernel_launch(void* const* d_in, const int* in_sizes, int n_in,
                              void* d_out, int out_size, void* d_ws, size_t ws_size,
                              hipStream_t stream) {
  const float* x    = (const float*)d_in[0];
  const float* ea   = (const float*)d_in[1];
  const int*   ei   = (const int*)d_in[2];
  const float* eps1 = (const float*)d_in[4];
  const float* el1w = (const float*)d_in[5];
  const float* el1b = (const float*)d_in[6];
  const float* n1w1 = (const float*)d_in[7];
  const float* n1b1 = (const float*)d_in[8];
  const float* n1g  = (const float*)d_in[9];
  const float* n1bt = (const float*)d_in[10];
  const float* n1w2 = (const float*)d_in[11];
  const float* n1b2 = (const float*)d_in[12];
  const float* eps2 = (const float*)d_in[13];
  const float* el2w = (const float*)d_in[14];
  const float* el2b = (const float*)d_in[15];
  const float* n2w1 = (const float*)d_in[16];
  const float* n2b1 = (const float*)d_in[17];
  const float* n2g  = (const float*)d_in[18];
  const float* n2bt = (const float*)d_in[19];
  const float* n2w2 = (const float*)d_in[20];
  const float* n2b2 = (const float*)d_in[21];
  const float* regw = (const float*)d_in[22];
  const float* regb = (const float*)d_in[23];
  const float* endw = (const float*)d_in[24];
  const float* endb = (const float*)d_in[25];
  const int* srcp = ei;
  const int* dstp = ei + NE;

  const size_t BUF = 6600000;  // floats per big buffer
  size_t need = (2 * BUF + 384) * sizeof(float);
  if (ws_size < need) return;  // cannot run without scratch

  float* buf0 = (float*)d_ws;
  float* buf1 = buf0 + BUF;
  float* stats = buf1 + BUF;  // 128 doubles (sum,sumsq) then scale[64],shift[64]

  // ---- layer 1 ----
  float* t1 = buf1;                 // [N,64]
  float* agg1 = buf1 + NN * 64;     // [N,2]
  hipMemsetAsync(agg1, 0, NN * 2 * sizeof(float), stream);
  hipMemsetAsync(stats, 0, 128 * sizeof(double), stream);
  edge1_kernel<<<2048, 256, 0, stream>>>(x, ea, srcp, dstp, el1w, el1b, agg1);
  nodeA2_kernel<<<2048, 256, 0, stream>>>(x, agg1, t1, n1w1, n1b1, eps1, stats);
  statsfin_kernel<<<1, 64, 0, stream>>>(stats, n1g, n1bt);
  nodeB_kernel<<<2048, 256, 0, stream>>>(t1, buf1, n1w2, n1b2, stats);

  // ---- layers 2,3 (shared weights) ----
  float* cur = buf1;
  float* wrk = buf0;
  for (int l = 0; l < 2; l++) {
    hipMemsetAsync(wrk, 0, NN * 64 * sizeof(float), stream);
    hipMemsetAsync(stats, 0, 128 * sizeof(double), stream);
    edge64_kernel<<<2048, 256, 0, stream>>>(cur, ea, srcp, dstp, el2w, el2b, wrk);
    nodeA64_kernel<<<2048, 256, 0, stream>>>(cur, wrk, n2w1, n2b1, eps2, stats);
    statsfin_kernel<<<1, 64, 0, stream>>>(stats, n2g, n2bt);
    nodeB_kernel<<<2048, 256, 0, stream>>>(wrk, wrk, n2w2, n2b2, stats);
    float* tmp = cur; cur = wrk; wrk = tmp;
  }

  // ---- head ----
  final_kernel<<<(NN + 255) / 256, 256, 0, stream>>>(cur, regw, regb, endw, endb,
                                                     (float*)d_out);
}

// Round 2
// 2018.776 us; speedup vs baseline: 1.0612x; 1.0612x over previous
//
#include <hip/hip_runtime.h>

#define NN 100000
#define NE 3200000

// ===================== CSR build =====================
__global__ __launch_bounds__(256) void count_kernel(const int* __restrict__ dst,
                                                    int* __restrict__ cnt) {
  int stride = gridDim.x * 256;
  for (int e = blockIdx.x * 256 + threadIdx.x; e < NE; e += stride)
    atomicAdd(&cnt[dst[e]], 1);
}

// single-block exclusive scan over NN counts -> rowptr[0..NN]; ofs=running copy
// (ofs may alias cnt)
__global__ __launch_bounds__(1024) void scan_kernel(const int* __restrict__ cnt,
                                                    int* __restrict__ rowptr,
                                                    int* __restrict__ ofs) {
  __shared__ int bsum[1024];
  int tid = threadIdx.x;
  const int CH = (NN + 1023) / 1024;
  int lo = tid * CH, hi = lo + CH < NN ? lo + CH : NN;
  if (lo > NN) lo = NN;
  if (hi < lo) hi = lo;
  int s = 0;
  for (int i = lo; i < hi; i++) s += cnt[i];
  bsum[tid] = s;
  __syncthreads();
  for (int off = 1; off < 1024; off <<= 1) {
    int v = bsum[tid];
    int u = (tid >= off) ? bsum[tid - off] : 0;
    __syncthreads();
    bsum[tid] = v + u;
    __syncthreads();
  }
  int pre = (tid == 0) ? 0 : bsum[tid - 1];
  for (int i = lo; i < hi; i++) {
    int cv = cnt[i];
    rowptr[i] = pre;
    ofs[i] = pre;
    pre += cv;
  }
  if (tid == 1023) rowptr[NN] = pre;
}

// packed scatter: 32B per sorted edge = [ea0..ea6, src-as-float-bits]
__global__ __launch_bounds__(256) void scatter2_kernel(
    const int* __restrict__ src, const int* __restrict__ dst,
    const float* __restrict__ ea, int* __restrict__ ofs,
    float* __restrict__ pe) {
  int stride = gridDim.x * 256;
  for (int e = blockIdx.x * 256 + threadIdx.x; e < NE; e += stride) {
    int pos = atomicAdd(&ofs[dst[e]], 1);
    float4 a, b;
    a.x = ea[e * 7 + 0]; a.y = ea[e * 7 + 1]; a.z = ea[e * 7 + 2]; a.w = ea[e * 7 + 3];
    b.x = ea[e * 7 + 4]; b.y = ea[e * 7 + 5]; b.z = ea[e * 7 + 6];
    b.w = __int_as_float(src[e]);
    ((float4*)pe)[pos * 2 + 0] = a;
    ((float4*)pe)[pos * 2 + 1] = b;
  }
}

// slim scatter: sorted edge ids only
__global__ __launch_bounds__(256) void scatter1_kernel(
    const int* __restrict__ dst, int* __restrict__ ofs, int* __restrict__ eid_s) {
  int stride = gridDim.x * 256;
  for (int e = blockIdx.x * 256 + threadIdx.x; e < NE; e += stride) {
    int pos = atomicAdd(&ofs[dst[e]], 1);
    eid_s[pos] = e;
  }
}

// ===================== layer 1: CSR aggregate (thread per node, 2 channels) ==
template <bool PACKED>
__global__ __launch_bounds__(256) void l1agg_kernel(
    const int* __restrict__ rowptr, const void* __restrict__ edat,
    const int* __restrict__ src, const float* __restrict__ ea,
    const float* __restrict__ x, const float* __restrict__ elw,
    const float* __restrict__ elb, float* __restrict__ agg) {
  float w0[7], w1r[7];
#pragma unroll
  for (int k = 0; k < 7; k++) { w0[k] = elw[k * 2]; w1r[k] = elw[k * 2 + 1]; }
  float b0 = elb[0], b1 = elb[1];
  int stride = gridDim.x * 256;
  for (int n = blockIdx.x * 256 + threadIdx.x; n < NN; n += stride) {
    int r0 = rowptr[n], r1 = rowptr[n + 1];
    float a0 = 0.f, a1 = 0.f;
    for (int i = r0; i < r1; i++) {
      float av[7];
      int sn;
      if (PACKED) {
        const float4* pe = (const float4*)edat;
        float4 pa = pe[i * 2], pb = pe[i * 2 + 1];
        av[0] = pa.x; av[1] = pa.y; av[2] = pa.z; av[3] = pa.w;
        av[4] = pb.x; av[5] = pb.y; av[6] = pb.z;
        sn = __float_as_int(pb.w);
      } else {
        const int* eid_s = (const int*)edat;
        int e = eid_s[i];
        sn = src[e];
#pragma unroll
        for (int k = 0; k < 7; k++) av[k] = ea[e * 7 + k];
      }
      float m0 = b0, m1 = b1;
#pragma unroll
      for (int k = 0; k < 7; k++) {
        m0 = fmaf(av[k], w0[k], m0);
        m1 = fmaf(av[k], w1r[k], m1);
      }
      m0 = fmaxf(m0 + x[sn * 2 + 0], 0.f);
      m1 = fmaxf(m1 + x[sn * 2 + 1], 0.f);
      a0 += m0; a1 += m1;
    }
    agg[n * 2 + 0] = a0;
    agg[n * 2 + 1] = a1;
  }
}

// ========== layers 2/3 fused: CSR aggregate + h + w1 matmul + BN stats =======
template <bool PACKED>
__global__ __launch_bounds__(256) void gine64_csr_kernel(
    const int* __restrict__ rowptr, const void* __restrict__ edat,
    const int* __restrict__ src, const float* __restrict__ ea,
    const float* __restrict__ xin, const float* __restrict__ elw,
    const float* __restrict__ elb, const float* __restrict__ w1,
    const float* __restrict__ b1, const float* __restrict__ eps_p,
    float* __restrict__ tbuf, float* __restrict__ stats) {
  __shared__ float wl[64 * 64];
  __shared__ float hb[4][64];
  __shared__ float red[256];
  int tid = threadIdx.x, lane = tid & 63, wv = tid >> 6;
  for (int i = tid; i < 64 * 64; i += 256) wl[i] = w1[i];
  float wel[7];
#pragma unroll
  for (int k = 0; k < 7; k++) wel[k] = elw[k * 64 + lane];
  float bel = elb[lane], b1c = b1[lane];
  float ep = 1.0f + *eps_p;
  float s = 0.f, ss = 0.f;
  __syncthreads();
  int nw = gridDim.x * 4;
  for (int n = blockIdx.x * 4 + wv; n < NN; n += nw) {
    int r0 = rowptr[n], r1 = rowptr[n + 1];
    float acc = 0.f;
    if (PACKED) {
      const float4* pe = (const float4*)edat;
      for (int i = r0; i < r1; i++) {
        float4 pa = pe[i * 2], pb = pe[i * 2 + 1];
        int sn = __float_as_int(pb.w);
        float m = bel;
        m = fmaf(pa.x, wel[0], m);
        m = fmaf(pa.y, wel[1], m);
        m = fmaf(pa.z, wel[2], m);
        m = fmaf(pa.w, wel[3], m);
        m = fmaf(pb.x, wel[4], m);
        m = fmaf(pb.y, wel[5], m);
        m = fmaf(pb.z, wel[6], m);
        m += xin[sn * 64 + lane];
        acc += fmaxf(m, 0.f);
      }
    } else {
      const int* eid_s = (const int*)edat;
      for (int i = r0; i < r1; i++) {
        int e = eid_s[i];
        int sn = src[e];
        float m = bel;
#pragma unroll
        for (int k = 0; k < 7; k++) m = fmaf(ea[e * 7 + k], wel[k], m);
        m += xin[sn * 64 + lane];
        acc += fmaxf(m, 0.f);
      }
    }
    float h = ep * xin[n * 64 + lane] + acc;
    hb[wv][lane] = h;  // same-wave LDS exchange, DS pipe is in-order per wave
    float t = b1c;
#pragma unroll
    for (int k = 0; k < 64; k++) t = fmaf(hb[wv][k], wl[k * 64 + lane], t);
    tbuf[n * 64 + lane] = t;
    s += t;
    ss += t * t;
  }
  double* dsum = (double*)stats;
  red[tid] = s;
  __syncthreads();
  if (tid < 64) unsafeAtomicAdd(&dsum[tid], (double)(red[tid] + red[tid + 64] + red[tid + 128] + red[tid + 192]));
  __syncthreads();
  red[tid] = ss;
  __syncthreads();
  if (tid < 64) unsafeAtomicAdd(&dsum[64 + tid], (double)(red[tid] + red[tid + 64] + red[tid + 128] + red[tid + 192]));
}

// ===================== legacy (fallback tier) kernels ========================
__global__ __launch_bounds__(256) void edge1_kernel(
    const float* __restrict__ x, const float* __restrict__ ea,
    const int* __restrict__ src, const int* __restrict__ dst,
    const float* __restrict__ elw, const float* __restrict__ elb,
    float* __restrict__ agg) {
  float w0[7], w1[7];
#pragma unroll
  for (int k = 0; k < 7; k++) { w0[k] = elw[k * 2]; w1[k] = elw[k * 2 + 1]; }
  float b0 = elb[0], b1 = elb[1];
  int stride = gridDim.x * 256;
  for (int e = blockIdx.x * 256 + threadIdx.x; e < NE; e += stride) {
    int s = src[e], d = dst[e];
    float m0 = b0, m1 = b1;
#pragma unroll
    for (int k = 0; k < 7; k++) {
      float a = ea[e * 7 + k];
      m0 = fmaf(a, w0[k], m0);
      m1 = fmaf(a, w1[k], m1);
    }
    m0 = fmaxf(m0 + x[s * 2 + 0], 0.f);
    m1 = fmaxf(m1 + x[s * 2 + 1], 0.f);
    unsafeAtomicAdd(&agg[d * 2 + 0], m0);
    unsafeAtomicAdd(&agg[d * 2 + 1], m1);
  }
}

__global__ __launch_bounds__(256) void edge64_kernel(
    const float* __restrict__ xin, const float* __restrict__ ea,
    const int* __restrict__ src, const int* __restrict__ dst,
    const float* __restrict__ elw, const float* __restrict__ elb,
    float* __restrict__ agg) {
  int lane = threadIdx.x & 63;
  int wid = (blockIdx.x * 256 + threadIdx.x) >> 6;
  int nw = (gridDim.x * 256) >> 6;
  float w[7];
#pragma unroll
  for (int k = 0; k < 7; k++) w[k] = elw[k * 64 + lane];
  float b = elb[lane];
  for (int e = wid; e < NE; e += nw) {
    int eu = __builtin_amdgcn_readfirstlane(e);
    int s = src[eu];
    int d = dst[eu];
    float m = b;
#pragma unroll
    for (int k = 0; k < 7; k++) m = fmaf(ea[eu * 7 + k], w[k], m);
    m += xin[s * 64 + lane];
    m = fmaxf(m, 0.f);
    unsafeAtomicAdd(&agg[d * 64 + lane], m);
  }
}

__global__ __launch_bounds__(256) void nodeA64_kernel(
    const float* __restrict__ xin, float* __restrict__ tbuf,
    const float* __restrict__ w1, const float* __restrict__ b1,
    const float* __restrict__ eps_p, float* __restrict__ stats) {
  __shared__ float wl[64 * 64];
  __shared__ float hbuf[4][64];
  __shared__ float red[256];
  int tid = threadIdx.x;
  int c = tid & 63, nl = tid >> 6;
  for (int i = tid; i < 64 * 64; i += 256) wl[i] = w1[i];
  float ep = 1.0f + *eps_p;
  float bc = b1[c];
  float s = 0.f, ss = 0.f;
  __syncthreads();
  for (int n0 = blockIdx.x * 4; n0 < NN; n0 += gridDim.x * 4) {
    int n = n0 + nl;
    bool valid = n < NN;
    float h = 0.f;
    if (valid) h = ep * xin[n * 64 + c] + tbuf[n * 64 + c];
    hbuf[nl][c] = h;
    __syncthreads();
    if (valid) {
      float t = bc;
#pragma unroll
      for (int k = 0; k < 64; k++) t = fmaf(hbuf[nl][k], wl[k * 64 + c], t);
      tbuf[n * 64 + c] = t;
      s += t;
      ss += t * t;
    }
    __syncthreads();
  }
  double* dsum = (double*)stats;
  red[tid] = s;
  __syncthreads();
  if (tid < 64) unsafeAtomicAdd(&dsum[tid], (double)(red[tid] + red[tid + 64] + red[tid + 128] + red[tid + 192]));
  __syncthreads();
  red[tid] = ss;
  __syncthreads();
  if (tid < 64) unsafeAtomicAdd(&dsum[64 + tid], (double)(red[tid] + red[tid + 64] + red[tid + 128] + red[tid + 192]));
}

// ===================== shared node kernels ===================================
__global__ __launch_bounds__(256) void nodeA2_kernel(
    const float* __restrict__ x, const float* __restrict__ agg1,
    float* __restrict__ tbuf, const float* __restrict__ w1,
    const float* __restrict__ b1, const float* __restrict__ eps_p,
    float* __restrict__ stats) {
  __shared__ float red[256];
  int tid = threadIdx.x;
  int c = tid & 63, nl = tid >> 6;
  float wa = w1[c], wb = w1[64 + c], bc = b1[c];
  float ep = 1.0f + *eps_p;
  float s = 0.f, ss = 0.f;
  for (int n0 = blockIdx.x * 4; n0 < NN; n0 += gridDim.x * 4) {
    int n = n0 + nl;
    if (n < NN) {
      float h0 = ep * x[n * 2 + 0] + agg1[n * 2 + 0];
      float h1 = ep * x[n * 2 + 1] + agg1[n * 2 + 1];
      float t = fmaf(h1, wb, fmaf(h0, wa, bc));
      tbuf[n * 64 + c] = t;
      s += t;
      ss += t * t;
    }
  }
  double* dsum = (double*)stats;
  red[tid] = s;
  __syncthreads();
  if (tid < 64) unsafeAtomicAdd(&dsum[tid], (double)(red[tid] + red[tid + 64] + red[tid + 128] + red[tid + 192]));
  __syncthreads();
  red[tid] = ss;
  __syncthreads();
  if (tid < 64) unsafeAtomicAdd(&dsum[64 + tid], (double)(red[tid] + red[tid + 64] + red[tid + 128] + red[tid + 192]));
}

__global__ void statsfin_kernel(float* stats, const float* __restrict__ g,
                                const float* __restrict__ bt) {
  int c = threadIdx.x;  // 64 threads
  const double* ds = (const double*)stats;
  double m = ds[c] / (double)NN;
  double v = ds[64 + c] / (double)NN - m * m;
  float sc = g[c] * (float)(1.0 / sqrt(v + 1e-5));
  stats[256 + c] = sc;
  stats[320 + c] = bt[c] - (float)m * sc;
}

__global__ __launch_bounds__(256) void nodeB_kernel(
    const float* __restrict__ tin, float* __restrict__ outb,
    const float* __restrict__ w2, const float* __restrict__ b2,
    const float* __restrict__ stats) {
  __shared__ float wl[64 * 64];
  __shared__ float ubuf[4][64];
  int tid = threadIdx.x;
  int c = tid & 63, nl = tid >> 6;
  for (int i = tid; i < 64 * 64; i += 256) wl[i] = w2[i];
  float scale = stats[256 + c], shift = stats[320 + c], bc = b2[c];
  __syncthreads();
  for (int n0 = blockIdx.x * 4; n0 < NN; n0 += gridDim.x * 4) {
    int n = n0 + nl;
    bool valid = n < NN;
    float u = 0.f;
    if (valid) {
      float t = tin[n * 64 + c];
      u = fmaxf(fmaf(t, scale, shift), 0.f);
    }
    ubuf[nl][c] = u;
    __syncthreads();
    if (valid) {
      float o = bc;
#pragma unroll
      for (int k = 0; k < 64; k++) o = fmaf(ubuf[nl][k], wl[k * 64 + c], o);
      outb[n * 64 + c] = fmaxf(o, 0.f);
    }
    __syncthreads();
  }
}

__global__ __launch_bounds__(256) void final_kernel(
    const float* __restrict__ xin, const float* __restrict__ regw,
    const float* __restrict__ regb, const float* __restrict__ endw,
    const float* __restrict__ endb, float* __restrict__ out) {
  __shared__ float wl[64 * 128];
  __shared__ float eb[256];
  int tid = threadIdx.x;
  int node = blockIdx.x * 256 + tid;
  bool valid = node < NN;
  float xr[64];
  if (valid) {
    const float4* xp = (const float4*)(xin + node * 64);
#pragma unroll
    for (int k4 = 0; k4 < 16; k4++) {
      float4 v = xp[k4];
      xr[k4 * 4 + 0] = v.x; xr[k4 * 4 + 1] = v.y;
      xr[k4 * 4 + 2] = v.z; xr[k4 * 4 + 3] = v.w;
    }
  }
  float y = 0.f;
  for (int ch = 0; ch < 4; ch++) {
    int j0 = ch * 125;
    __syncthreads();
    for (int idx = tid; idx < 64 * 125; idx += 256) {
      int k = idx / 125;
      int jl = idx - k * 125;
      wl[k * 128 + jl] = regw[k * 500 + j0 + jl];
    }
    if (tid < 125) { eb[tid] = regb[j0 + tid]; eb[128 + tid] = endw[j0 + tid]; }
    __syncthreads();
    if (valid) {
      int jl = 0;
      for (; jl + 4 <= 125; jl += 4) {
        float t0 = eb[jl], t1 = eb[jl + 1], t2 = eb[jl + 2], t3 = eb[jl + 3];
#pragma unroll
        for (int k = 0; k < 64; k++) {
          float4 w4 = *(const float4*)&wl[k * 128 + jl];
          float xv = xr[k];
          t0 = fmaf(xv, w4.x, t0);
          t1 = fmaf(xv, w4.y, t1);
          t2 = fmaf(xv, w4.z, t2);
          t3 = fmaf(xv, w4.w, t3);
        }
        t0 = t0 >= 0.f ? t0 : 0.01f * t0;
        t1 = t1 >= 0.f ? t1 : 0.01f * t1;
        t2 = t2 >= 0.f ? t2 : 0.01f * t2;
        t3 = t3 >= 0.f ? t3 : 0.01f * t3;
        y += t0 * eb[128 + jl] + t1 * eb[128 + jl + 1] + t2 * eb[128 + jl + 2] + t3 * eb[128 + jl + 3];
      }
      {
        float t = eb[124];
#pragma unroll
        for (int k = 0; k < 64; k++) t = fmaf(xr[k], wl[k * 128 + 124], t);
        t = t >= 0.f ? t : 0.01f * t;
        y += t * eb[128 + 124];
      }
    }
  }
  if (valid) out[node] = y + endb[0];
}

extern "C" void kernel_launch(void* const* d_in, const int* in_sizes, int n_in,
                              void* d_out, int out_size, void* d_ws, size_t ws_size,
                              hipStream_t stream) {
  const float* x    = (const float*)d_in[0];
  const float* ea   = (const float*)d_in[1];
  const int*   ei   = (const int*)d_in[2];
  const float* eps1 = (const float*)d_in[4];
  const float* el1w = (const float*)d_in[5];
  const float* el1b = (const float*)d_in[6];
  const float* n1w1 = (const float*)d_in[7];
  const float* n1b1 = (const float*)d_in[8];
  const float* n1g  = (const float*)d_in[9];
  const float* n1bt = (const float*)d_in[10];
  const float* n1w2 = (const float*)d_in[11];
  const float* n1b2 = (const float*)d_in[12];
  const float* eps2 = (const float*)d_in[13];
  const float* el2w = (const float*)d_in[14];
  const float* el2b = (const float*)d_in[15];
  const float* n2w1 = (const float*)d_in[16];
  const float* n2b1 = (const float*)d_in[17];
  const float* n2g  = (const float*)d_in[18];
  const float* n2bt = (const float*)d_in[19];
  const float* n2w2 = (const float*)d_in[20];
  const float* n2b2 = (const float*)d_in[21];
  const float* regw = (const float*)d_in[22];
  const float* regb = (const float*)d_in[23];
  const float* endw = (const float*)d_in[24];
  const float* endb = (const float*)d_in[25];
  const int* srcp = ei;
  const int* dstp = ei + NE;

  // ---- tier-A layout (floats) ----
  const size_t o_stats  = 0;         // 512 floats (128 doubles + scale/shift)
  const size_t o_rowptr = 512;       // NN+1 ints
  const size_t o_cnt    = 100516;    // NN ints (doubles as scatter offsets)
  const size_t o_buf0   = 200576;    // N*64 floats (256B aligned)
  const size_t o_buf1   = 6600576;   // N*64 floats
  const size_t o_agg1   = 13000576;  // N*2 floats
  const size_t o_edat   = 13200576;  // packed: E*8 floats | slim: E ints
  const size_t needA2 = (o_edat + (size_t)NE * 8) * 4;  // ~155.2 MB
  const size_t needA1 = (o_edat + (size_t)NE) * 4;      // ~65.6 MB
  const size_t needB  = (2 * 6600000 + 384) * 4;        // ~52.8 MB

  float* wsf = (float*)d_ws;

  if (ws_size >= needA1) {
    const bool packed = ws_size >= needA2;
    float* stats = wsf + o_stats;
    int* rowptr  = (int*)(wsf + o_rowptr);
    int* cnt     = (int*)(wsf + o_cnt);
    float* buf0  = wsf + o_buf0;
    float* buf1  = wsf + o_buf1;
    float* agg1  = wsf + o_agg1;
    void* edat   = (void*)(wsf + o_edat);

    // ---- CSR build (once, shared by all 3 layers) ----
    hipMemsetAsync(cnt, 0, NN * sizeof(int), stream);
    count_kernel<<<4096, 256, 0, stream>>>(dstp, cnt);
    scan_kernel<<<1, 1024, 0, stream>>>(cnt, rowptr, cnt);
    if (packed)
      scatter2_kernel<<<4096, 256, 0, stream>>>(srcp, dstp, ea, cnt, (float*)edat);
    else
      scatter1_kernel<<<4096, 256, 0, stream>>>(dstp, cnt, (int*)edat);

    // ---- layer 1 ----
    hipMemsetAsync(stats, 0, 128 * sizeof(double), stream);
    if (packed)
      l1agg_kernel<true><<<391, 256, 0, stream>>>(rowptr, edat, srcp, ea, x, el1w, el1b, agg1);
    else
      l1agg_kernel<false><<<391, 256, 0, stream>>>(rowptr, edat, srcp, ea, x, el1w, el1b, agg1);
    nodeA2_kernel<<<2048, 256, 0, stream>>>(x, agg1, buf1, n1w1, n1b1, eps1, stats);
    statsfin_kernel<<<1, 64, 0, stream>>>(stats, n1g, n1bt);
    nodeB_kernel<<<2048, 256, 0, stream>>>(buf1, buf1, n1w2, n1b2, stats);

    // ---- layers 2,3 (shared weights) ----
    float* cur = buf1;
    float* wrk = buf0;
    for (int l = 0; l < 2; l++) {
      hipMemsetAsync(stats, 0, 128 * sizeof(double), stream);
      if (packed)
        gine64_csr_kernel<true><<<4096, 256, 0, stream>>>(rowptr, edat, srcp, ea,
            cur, el2w, el2b, n2w1, n2b1, eps2, wrk, stats);
      else
        gine64_csr_kernel<false><<<4096, 256, 0, stream>>>(rowptr, edat, srcp, ea,
            cur, el2w, el2b, n2w1, n2b1, eps2, wrk, stats);
      statsfin_kernel<<<1, 64, 0, stream>>>(stats, n2g, n2bt);
      nodeB_kernel<<<2048, 256, 0, stream>>>(wrk, wrk, n2w2, n2b2, stats);
      float* tmp = cur; cur = wrk; wrk = tmp;
    }

    final_kernel<<<(NN + 255) / 256, 256, 0, stream>>>(cur, regw, regb, endw, endb,
                                                       (float*)d_out);
    return;
  }

  // ================= fallback tier B (round-1 proven path) =================
  if (ws_size < needB) return;
  const size_t BUF = 6600000;
  float* buf0 = (float*)d_ws;
  float* buf1 = buf0 + BUF;
  float* stats = buf1 + BUF;

  float* t1 = buf1;
  float* agg1 = buf1 + NN * 64;
  hipMemsetAsync(agg1, 0, NN * 2 * sizeof(float), stream);
  hipMemsetAsync(stats, 0, 128 * sizeof(double), stream);
  edge1_kernel<<<2048, 256, 0, stream>>>(x, ea, srcp, dstp, el1w, el1b, agg1);
  nodeA2_kernel<<<2048, 256, 0, stream>>>(x, agg1, t1, n1w1, n1b1, eps1, stats);
  statsfin_kernel<<<1, 64, 0, stream>>>(stats, n1g, n1bt);
  nodeB_kernel<<<2048, 256, 0, stream>>>(t1, buf1, n1w2, n1b2, stats);

  float* cur = buf1;
  float* wrk = buf0;
  for (int l = 0; l < 2; l++) {
    hipMemsetAsync(wrk, 0, NN * 64 * sizeof(float), stream);
    hipMemsetAsync(stats, 0, 128 * sizeof(double), stream);
    edge64_kernel<<<2048, 256, 0, stream>>>(cur, ea, srcp, dstp, el2w, el2b, wrk);
    nodeA64_kernel<<<2048, 256, 0, stream>>>(cur, wrk, n2w1, n2b1, eps2, stats);
    statsfin_kernel<<<1, 64, 0, stream>>>(stats, n2g, n2bt);
    nodeB_kernel<<<2048, 256, 0, stream>>>(wrk, wrk, n2w2, n2b2, stats);
    float* tmp = cur; cur = wrk; wrk = tmp;
  }

  final_kernel<<<(NN + 255) / 256, 256, 0, stream>>>(cur, regw, regb, endw, endb,
                                                     (float*)d_out);
}

// Round 3
// 1534.772 us; speedup vs baseline: 1.3959x; 1.3154x over previous
//
#include <hip/hip_runtime.h>

#define NN 100000
#define NE 3200000

// ===================== CSR build =====================
__global__ __launch_bounds__(256) void count_kernel(const int* __restrict__ dst,
                                                    int* __restrict__ cnt) {
  int stride = gridDim.x * 256;
  for (int e = blockIdx.x * 256 + threadIdx.x; e < NE; e += stride)
    atomicAdd(&cnt[dst[e]], 1);
}

// single-block exclusive scan over NN counts -> rowptr[0..NN]; ofs=running copy
__global__ __launch_bounds__(1024) void scan_kernel(const int* __restrict__ cnt,
                                                    int* __restrict__ rowptr,
                                                    int* __restrict__ ofs) {
  __shared__ int bsum[1024];
  int tid = threadIdx.x;
  const int CH = (NN + 1023) / 1024;
  int lo = tid * CH, hi = lo + CH < NN ? lo + CH : NN;
  if (lo > NN) lo = NN;
  if (hi < lo) hi = lo;
  int s = 0;
  for (int i = lo; i < hi; i++) s += cnt[i];
  bsum[tid] = s;
  __syncthreads();
  for (int off = 1; off < 1024; off <<= 1) {
    int v = bsum[tid];
    int u = (tid >= off) ? bsum[tid - off] : 0;
    __syncthreads();
    bsum[tid] = v + u;
    __syncthreads();
  }
  int pre = (tid == 0) ? 0 : bsum[tid - 1];
  for (int i = lo; i < hi; i++) {
    int cv = cnt[i];
    rowptr[i] = pre;
    ofs[i] = pre;
    pre += cv;
  }
  if (tid == 1023) rowptr[NN] = pre;
}

// packed scatter + fused layer-1 message:
//   pe[pos]   = [ea0..ea6, src-as-float-bits]   (32B record)
//   msg1[pos] = relu(x[src,:2] + ea @ el1w + el1b)  ([E,2] sorted)
__global__ __launch_bounds__(256) void scatter2p_kernel(
    const int* __restrict__ src, const int* __restrict__ dst,
    const float* __restrict__ ea, int* __restrict__ ofs,
    float* __restrict__ pe, const float* __restrict__ x,
    const float* __restrict__ elw, const float* __restrict__ elb,
    float* __restrict__ msg1) {
  float w0[7], w1r[7];
#pragma unroll
  for (int k = 0; k < 7; k++) { w0[k] = elw[k * 2]; w1r[k] = elw[k * 2 + 1]; }
  float b0 = elb[0], b1 = elb[1];
  int stride = gridDim.x * 256;
  for (int e = blockIdx.x * 256 + threadIdx.x; e < NE; e += stride) {
    int sn = src[e];
    int pos = atomicAdd(&ofs[dst[e]], 1);
    float av[7];
#pragma unroll
    for (int k = 0; k < 7; k++) av[k] = ea[e * 7 + k];
    float4 a, b;
    a.x = av[0]; a.y = av[1]; a.z = av[2]; a.w = av[3];
    b.x = av[4]; b.y = av[5]; b.z = av[6];
    b.w = __int_as_float(sn);
    ((float4*)pe)[pos * 2 + 0] = a;
    ((float4*)pe)[pos * 2 + 1] = b;
    float m0 = b0, m1 = b1;
#pragma unroll
    for (int k = 0; k < 7; k++) {
      m0 = fmaf(av[k], w0[k], m0);
      m1 = fmaf(av[k], w1r[k], m1);
    }
    m0 = fmaxf(m0 + x[sn * 2 + 0], 0.f);
    m1 = fmaxf(m1 + x[sn * 2 + 1], 0.f);
    float2 mv; mv.x = m0; mv.y = m1;
    ((float2*)msg1)[pos] = mv;
  }
}

// slim scatter: sorted edge ids only
__global__ __launch_bounds__(256) void scatter1_kernel(
    const int* __restrict__ dst, int* __restrict__ ofs, int* __restrict__ eid_s) {
  int stride = gridDim.x * 256;
  for (int e = blockIdx.x * 256 + threadIdx.x; e < NE; e += stride) {
    int pos = atomicAdd(&ofs[dst[e]], 1);
    eid_s[pos] = e;
  }
}

// ============ layer 1 (packed tier): segment-sum of precomputed msg1 =========
__global__ __launch_bounds__(256) void l1sum_kernel(
    const int* __restrict__ rowptr, const float* __restrict__ msg1,
    float* __restrict__ agg) {
  int stride = gridDim.x * 256;
  for (int n = blockIdx.x * 256 + threadIdx.x; n < NN; n += stride) {
    int r0 = rowptr[n], r1 = rowptr[n + 1];
    float a0 = 0.f, a1 = 0.f;
    const float2* mp = (const float2*)msg1;
    for (int i = r0; i < r1; i++) {
      float2 v = mp[i];
      a0 += v.x;
      a1 += v.y;
    }
    agg[n * 2 + 0] = a0;
    agg[n * 2 + 1] = a1;
  }
}

// =========== layer 1 slim-tier aggregate (thread per node, eid CSR) ==========
__global__ __launch_bounds__(256) void l1agg_kernel(
    const int* __restrict__ rowptr, const int* __restrict__ eid_s,
    const int* __restrict__ src, const float* __restrict__ ea,
    const float* __restrict__ x, const float* __restrict__ elw,
    const float* __restrict__ elb, float* __restrict__ agg) {
  float w0[7], w1r[7];
#pragma unroll
  for (int k = 0; k < 7; k++) { w0[k] = elw[k * 2]; w1r[k] = elw[k * 2 + 1]; }
  float b0 = elb[0], b1 = elb[1];
  int stride = gridDim.x * 256;
  for (int n = blockIdx.x * 256 + threadIdx.x; n < NN; n += stride) {
    int r0 = rowptr[n], r1 = rowptr[n + 1];
    float a0 = 0.f, a1 = 0.f;
    for (int i = r0; i < r1; i++) {
      int e = eid_s[i];
      int sn = src[e];
      float m0 = b0, m1 = b1;
#pragma unroll
      for (int k = 0; k < 7; k++) {
        float a = ea[e * 7 + k];
        m0 = fmaf(a, w0[k], m0);
        m1 = fmaf(a, w1r[k], m1);
      }
      m0 = fmaxf(m0 + x[sn * 2 + 0], 0.f);
      m1 = fmaxf(m1 + x[sn * 2 + 1], 0.f);
      a0 += m0; a1 += m1;
    }
    agg[n * 2 + 0] = a0;
    agg[n * 2 + 1] = a1;
  }
}

// ====== layers 2/3 fused, PACKED + software-pipelined (4 gathers in flight) ==
__global__ __launch_bounds__(256) void gine64p_kernel(
    const int* __restrict__ rowptr, const float* __restrict__ edat,
    const float* __restrict__ xin, const float* __restrict__ elw,
    const float* __restrict__ elb, const float* __restrict__ w1,
    const float* __restrict__ b1, const float* __restrict__ eps_p,
    float* __restrict__ tbuf, float* __restrict__ stats) {
  __shared__ float wl[64 * 64];
  __shared__ float hb[4][64];
  __shared__ float red[256];
  int tid = threadIdx.x, lane = tid & 63, wv = tid >> 6;
  for (int i = tid; i < 64 * 64; i += 256) wl[i] = w1[i];
  float wel[7];
#pragma unroll
  for (int k = 0; k < 7; k++) wel[k] = elw[k * 64 + lane];
  float bel = elb[lane], b1c = b1[lane];
  float ep = 1.0f + *eps_p;
  float s = 0.f, ss = 0.f;
  __syncthreads();
  const float4* pe = (const float4*)edat;
  int nw = gridDim.x * 4;
  for (int n = blockIdx.x * 4 + wv; n < NN; n += nw) {
    int r0 = rowptr[n], r1 = rowptr[n + 1];
    float acc = 0.f;
    int i = r0;
    int rem = r1 - r0;
    if (rem >= 4) {
      float4 a0 = pe[2 * i + 0], b0 = pe[2 * i + 1];
      float4 a1 = pe[2 * i + 2], b1v = pe[2 * i + 3];
      float4 a2 = pe[2 * i + 4], b2 = pe[2 * i + 5];
      float4 a3 = pe[2 * i + 6], b3 = pe[2 * i + 7];
      while (true) {
        // issue 4 independent gathers
        float g0 = xin[__float_as_int(b0.w) * 64 + lane];
        float g1 = xin[__float_as_int(b1v.w) * 64 + lane];
        float g2 = xin[__float_as_int(b2.w) * 64 + lane];
        float g3 = xin[__float_as_int(b3.w) * 64 + lane];
        i += 4; rem -= 4;
        bool more = rem >= 4;
        int ip = more ? i : r0;  // dummy (valid) address when finishing
        // prefetch next group's records while gathers are in flight
        float4 na0 = pe[2 * ip + 0], nb0 = pe[2 * ip + 1];
        float4 na1 = pe[2 * ip + 2], nb1 = pe[2 * ip + 3];
        float4 na2 = pe[2 * ip + 4], nb2 = pe[2 * ip + 5];
        float4 na3 = pe[2 * ip + 6], nb3 = pe[2 * ip + 7];
        // edge projections (independent of gathers)
        float m0 = bel, m1 = bel, m2 = bel, m3 = bel;
        m0 = fmaf(a0.x, wel[0], m0); m0 = fmaf(a0.y, wel[1], m0);
        m0 = fmaf(a0.z, wel[2], m0); m0 = fmaf(a0.w, wel[3], m0);
        m0 = fmaf(b0.x, wel[4], m0); m0 = fmaf(b0.y, wel[5], m0);
        m0 = fmaf(b0.z, wel[6], m0);
        m1 = fmaf(a1.x, wel[0], m1); m1 = fmaf(a1.y, wel[1], m1);
        m1 = fmaf(a1.z, wel[2], m1); m1 = fmaf(a1.w, wel[3], m1);
        m1 = fmaf(b1v.x, wel[4], m1); m1 = fmaf(b1v.y, wel[5], m1);
        m1 = fmaf(b1v.z, wel[6], m1);
        m2 = fmaf(a2.x, wel[0], m2); m2 = fmaf(a2.y, wel[1], m2);
        m2 = fmaf(a2.z, wel[2], m2); m2 = fmaf(a2.w, wel[3], m2);
        m2 = fmaf(b2.x, wel[4], m2); m2 = fmaf(b2.y, wel[5], m2);
        m2 = fmaf(b2.z, wel[6], m2);
        m3 = fmaf(a3.x, wel[0], m3); m3 = fmaf(a3.y, wel[1], m3);
        m3 = fmaf(a3.z, wel[2], m3); m3 = fmaf(a3.w, wel[3], m3);
        m3 = fmaf(b3.x, wel[4], m3); m3 = fmaf(b3.y, wel[5], m3);
        m3 = fmaf(b3.z, wel[6], m3);
        acc += fmaxf(m0 + g0, 0.f);
        acc += fmaxf(m1 + g1, 0.f);
        acc += fmaxf(m2 + g2, 0.f);
        acc += fmaxf(m3 + g3, 0.f);
        a0 = na0; b0 = nb0; a1 = na1; b1v = nb1;
        a2 = na2; b2 = nb2; a3 = na3; b3 = nb3;
        if (!more) break;
      }
    }
    for (; i < r1; i++) {  // tail (0..3 edges)
      float4 pa = pe[i * 2], pb = pe[i * 2 + 1];
      float m = bel;
      m = fmaf(pa.x, wel[0], m); m = fmaf(pa.y, wel[1], m);
      m = fmaf(pa.z, wel[2], m); m = fmaf(pa.w, wel[3], m);
      m = fmaf(pb.x, wel[4], m); m = fmaf(pb.y, wel[5], m);
      m = fmaf(pb.z, wel[6], m);
      m += xin[__float_as_int(pb.w) * 64 + lane];
      acc += fmaxf(m, 0.f);
    }
    float h = ep * xin[n * 64 + lane] + acc;
    hb[wv][lane] = h;  // same-wave LDS exchange (in-order DS pipe)
    float t = b1c;
#pragma unroll
    for (int k = 0; k < 64; k++) t = fmaf(hb[wv][k], wl[k * 64 + lane], t);
    tbuf[n * 64 + lane] = t;
    s += t;
    ss += t * t;
  }
  double* dsum = (double*)stats;
  red[tid] = s;
  __syncthreads();
  if (tid < 64) unsafeAtomicAdd(&dsum[tid], (double)(red[tid] + red[tid + 64] + red[tid + 128] + red[tid + 192]));
  __syncthreads();
  red[tid] = ss;
  __syncthreads();
  if (tid < 64) unsafeAtomicAdd(&dsum[64 + tid], (double)(red[tid] + red[tid + 64] + red[tid + 128] + red[tid + 192]));
}

// ====== layers 2/3 slim-tier (eid CSR, unpipelined — fallback only) ==========
__global__ __launch_bounds__(256) void gine64s_kernel(
    const int* __restrict__ rowptr, const int* __restrict__ eid_s,
    const int* __restrict__ src, const float* __restrict__ ea,
    const float* __restrict__ xin, const float* __restrict__ elw,
    const float* __restrict__ elb, const float* __restrict__ w1,
    const float* __restrict__ b1, const float* __restrict__ eps_p,
    float* __restrict__ tbuf, float* __restrict__ stats) {
  __shared__ float wl[64 * 64];
  __shared__ float hb[4][64];
  __shared__ float red[256];
  int tid = threadIdx.x, lane = tid & 63, wv = tid >> 6;
  for (int i = tid; i < 64 * 64; i += 256) wl[i] = w1[i];
  float wel[7];
#pragma unroll
  for (int k = 0; k < 7; k++) wel[k] = elw[k * 64 + lane];
  float bel = elb[lane], b1c = b1[lane];
  float ep = 1.0f + *eps_p;
  float s = 0.f, ss = 0.f;
  __syncthreads();
  int nw = gridDim.x * 4;
  for (int n = blockIdx.x * 4 + wv; n < NN; n += nw) {
    int r0 = rowptr[n], r1 = rowptr[n + 1];
    float acc = 0.f;
    for (int i = r0; i < r1; i++) {
      int e = eid_s[i];
      int sn = src[e];
      float m = bel;
#pragma unroll
      for (int k = 0; k < 7; k++) m = fmaf(ea[e * 7 + k], wel[k], m);
      m += xin[sn * 64 + lane];
      acc += fmaxf(m, 0.f);
    }
    float h = ep * xin[n * 64 + lane] + acc;
    hb[wv][lane] = h;
    float t = b1c;
#pragma unroll
    for (int k = 0; k < 64; k++) t = fmaf(hb[wv][k], wl[k * 64 + lane], t);
    tbuf[n * 64 + lane] = t;
    s += t;
    ss += t * t;
  }
  double* dsum = (double*)stats;
  red[tid] = s;
  __syncthreads();
  if (tid < 64) unsafeAtomicAdd(&dsum[tid], (double)(red[tid] + red[tid + 64] + red[tid + 128] + red[tid + 192]));
  __syncthreads();
  red[tid] = ss;
  __syncthreads();
  if (tid < 64) unsafeAtomicAdd(&dsum[64 + tid], (double)(red[tid] + red[tid + 64] + red[tid + 128] + red[tid + 192]));
}

// ===================== legacy (fallback tier B) kernels ======================
__global__ __launch_bounds__(256) void edge1_kernel(
    const float* __restrict__ x, const float* __restrict__ ea,
    const int* __restrict__ src, const int* __restrict__ dst,
    const float* __restrict__ elw, const float* __restrict__ elb,
    float* __restrict__ agg) {
  float w0[7], w1[7];
#pragma unroll
  for (int k = 0; k < 7; k++) { w0[k] = elw[k * 2]; w1[k] = elw[k * 2 + 1]; }
  float b0 = elb[0], b1 = elb[1];
  int stride = gridDim.x * 256;
  for (int e = blockIdx.x * 256 + threadIdx.x; e < NE; e += stride) {
    int s = src[e], d = dst[e];
    float m0 = b0, m1 = b1;
#pragma unroll
    for (int k = 0; k < 7; k++) {
      float a = ea[e * 7 + k];
      m0 = fmaf(a, w0[k], m0);
      m1 = fmaf(a, w1[k], m1);
    }
    m0 = fmaxf(m0 + x[s * 2 + 0], 0.f);
    m1 = fmaxf(m1 + x[s * 2 + 1], 0.f);
    unsafeAtomicAdd(&agg[d * 2 + 0], m0);
    unsafeAtomicAdd(&agg[d * 2 + 1], m1);
  }
}

__global__ __launch_bounds__(256) void edge64_kernel(
    const float* __restrict__ xin, const float* __restrict__ ea,
    const int* __restrict__ src, const int* __restrict__ dst,
    const float* __restrict__ elw, const float* __restrict__ elb,
    float* __restrict__ agg) {
  int lane = threadIdx.x & 63;
  int wid = (blockIdx.x * 256 + threadIdx.x) >> 6;
  int nw = (gridDim.x * 256) >> 6;
  float w[7];
#pragma unroll
  for (int k = 0; k < 7; k++) w[k] = elw[k * 64 + lane];
  float b = elb[lane];
  for (int e = wid; e < NE; e += nw) {
    int eu = __builtin_amdgcn_readfirstlane(e);
    int s = src[eu];
    int d = dst[eu];
    float m = b;
#pragma unroll
    for (int k = 0; k < 7; k++) m = fmaf(ea[eu * 7 + k], w[k], m);
    m += xin[s * 64 + lane];
    m = fmaxf(m, 0.f);
    unsafeAtomicAdd(&agg[d * 64 + lane], m);
  }
}

__global__ __launch_bounds__(256) void nodeA64_kernel(
    const float* __restrict__ xin, float* __restrict__ tbuf,
    const float* __restrict__ w1, const float* __restrict__ b1,
    const float* __restrict__ eps_p, float* __restrict__ stats) {
  __shared__ float wl[64 * 64];
  __shared__ float hbuf[4][64];
  __shared__ float red[256];
  int tid = threadIdx.x;
  int c = tid & 63, nl = tid >> 6;
  for (int i = tid; i < 64 * 64; i += 256) wl[i] = w1[i];
  float ep = 1.0f + *eps_p;
  float bc = b1[c];
  float s = 0.f, ss = 0.f;
  __syncthreads();
  for (int n0 = blockIdx.x * 4; n0 < NN; n0 += gridDim.x * 4) {
    int n = n0 + nl;
    bool valid = n < NN;
    float h = 0.f;
    if (valid) h = ep * xin[n * 64 + c] + tbuf[n * 64 + c];
    hbuf[nl][c] = h;
    __syncthreads();
    if (valid) {
      float t = bc;
#pragma unroll
      for (int k = 0; k < 64; k++) t = fmaf(hbuf[nl][k], wl[k * 64 + c], t);
      tbuf[n * 64 + c] = t;
      s += t;
      ss += t * t;
    }
    __syncthreads();
  }
  double* dsum = (double*)stats;
  red[tid] = s;
  __syncthreads();
  if (tid < 64) unsafeAtomicAdd(&dsum[tid], (double)(red[tid] + red[tid + 64] + red[tid + 128] + red[tid + 192]));
  __syncthreads();
  red[tid] = ss;
  __syncthreads();
  if (tid < 64) unsafeAtomicAdd(&dsum[64 + tid], (double)(red[tid] + red[tid + 64] + red[tid + 128] + red[tid + 192]));
}

// ===================== shared node kernels ===================================
__global__ __launch_bounds__(256) void nodeA2_kernel(
    const float* __restrict__ x, const float* __restrict__ agg1,
    float* __restrict__ tbuf, const float* __restrict__ w1,
    const float* __restrict__ b1, const float* __restrict__ eps_p,
    float* __restrict__ stats) {
  __shared__ float red[256];
  int tid = threadIdx.x;
  int c = tid & 63, nl = tid >> 6;
  float wa = w1[c], wb = w1[64 + c], bc = b1[c];
  float ep = 1.0f + *eps_p;
  float s = 0.f, ss = 0.f;
  for (int n0 = blockIdx.x * 4; n0 < NN; n0 += gridDim.x * 4) {
    int n = n0 + nl;
    if (n < NN) {
      float h0 = ep * x[n * 2 + 0] + agg1[n * 2 + 0];
      float h1 = ep * x[n * 2 + 1] + agg1[n * 2 + 1];
      float t = fmaf(h1, wb, fmaf(h0, wa, bc));
      tbuf[n * 64 + c] = t;
      s += t;
      ss += t * t;
    }
  }
  double* dsum = (double*)stats;
  red[tid] = s;
  __syncthreads();
  if (tid < 64) unsafeAtomicAdd(&dsum[tid], (double)(red[tid] + red[tid + 64] + red[tid + 128] + red[tid + 192]));
  __syncthreads();
  red[tid] = ss;
  __syncthreads();
  if (tid < 64) unsafeAtomicAdd(&dsum[64 + tid], (double)(red[tid] + red[tid + 64] + red[tid + 128] + red[tid + 192]));
}

__global__ void statsfin_kernel(float* stats, const float* __restrict__ g,
                                const float* __restrict__ bt) {
  int c = threadIdx.x;  // 64 threads
  const double* ds = (const double*)stats;
  double m = ds[c] / (double)NN;
  double v = ds[64 + c] / (double)NN - m * m;
  float sc = g[c] * (float)(1.0 / sqrt(v + 1e-5));
  stats[256 + c] = sc;
  stats[320 + c] = bt[c] - (float)m * sc;
}

__global__ __launch_bounds__(256) void nodeB_kernel(
    const float* __restrict__ tin, float* __restrict__ outb,
    const float* __restrict__ w2, const float* __restrict__ b2,
    const float* __restrict__ stats) {
  __shared__ float wl[64 * 64];
  __shared__ float ubuf[4][64];
  int tid = threadIdx.x;
  int c = tid & 63, nl = tid >> 6;
  for (int i = tid; i < 64 * 64; i += 256) wl[i] = w2[i];
  float scale = stats[256 + c], shift = stats[320 + c], bc = b2[c];
  __syncthreads();
  for (int n0 = blockIdx.x * 4; n0 < NN; n0 += gridDim.x * 4) {
    int n = n0 + nl;
    bool valid = n < NN;
    float u = 0.f;
    if (valid) {
      float t = tin[n * 64 + c];
      u = fmaxf(fmaf(t, scale, shift), 0.f);
    }
    ubuf[nl][c] = u;
    __syncthreads();
    if (valid) {
      float o = bc;
#pragma unroll
      for (int k = 0; k < 64; k++) o = fmaf(ubuf[nl][k], wl[k * 64 + c], o);
      outb[n * 64 + c] = fmaxf(o, 0.f);
    }
    __syncthreads();
  }
}

__global__ __launch_bounds__(256) void final_kernel(
    const float* __restrict__ xin, const float* __restrict__ regw,
    const float* __restrict__ regb, const float* __restrict__ endw,
    const float* __restrict__ endb, float* __restrict__ out) {
  __shared__ float wl[64 * 128];
  __shared__ float eb[256];
  int tid = threadIdx.x;
  int node = blockIdx.x * 256 + tid;
  bool valid = node < NN;
  float xr[64];
  if (valid) {
    const float4* xp = (const float4*)(xin + node * 64);
#pragma unroll
    for (int k4 = 0; k4 < 16; k4++) {
      float4 v = xp[k4];
      xr[k4 * 4 + 0] = v.x; xr[k4 * 4 + 1] = v.y;
      xr[k4 * 4 + 2] = v.z; xr[k4 * 4 + 3] = v.w;
    }
  }
  float y = 0.f;
  for (int ch = 0; ch < 4; ch++) {
    int j0 = ch * 125;
    __syncthreads();
    for (int idx = tid; idx < 64 * 125; idx += 256) {
      int k = idx / 125;
      int jl = idx - k * 125;
      wl[k * 128 + jl] = regw[k * 500 + j0 + jl];
    }
    if (tid < 125) { eb[tid] = regb[j0 + tid]; eb[128 + tid] = endw[j0 + tid]; }
    __syncthreads();
    if (valid) {
      int jl = 0;
      for (; jl + 4 <= 125; jl += 4) {
        float t0 = eb[jl], t1 = eb[jl + 1], t2 = eb[jl + 2], t3 = eb[jl + 3];
#pragma unroll
        for (int k = 0; k < 64; k++) {
          float4 w4 = *(const float4*)&wl[k * 128 + jl];
          float xv = xr[k];
          t0 = fmaf(xv, w4.x, t0);
          t1 = fmaf(xv, w4.y, t1);
          t2 = fmaf(xv, w4.z, t2);
          t3 = fmaf(xv, w4.w, t3);
        }
        t0 = t0 >= 0.f ? t0 : 0.01f * t0;
        t1 = t1 >= 0.f ? t1 : 0.01f * t1;
        t2 = t2 >= 0.f ? t2 : 0.01f * t2;
        t3 = t3 >= 0.f ? t3 : 0.01f * t3;
        y += t0 * eb[128 + jl] + t1 * eb[128 + jl + 1] + t2 * eb[128 + jl + 2] + t3 * eb[128 + jl + 3];
      }
      {
        float t = eb[124];
#pragma unroll
        for (int k = 0; k < 64; k++) t = fmaf(xr[k], wl[k * 128 + 124], t);
        t = t >= 0.f ? t : 0.01f * t;
        y += t * eb[128 + 124];
      }
    }
  }
  if (valid) out[node] = y + endb[0];
}

extern "C" void kernel_launch(void* const* d_in, const int* in_sizes, int n_in,
                              void* d_out, int out_size, void* d_ws, size_t ws_size,
                              hipStream_t stream) {
  const float* x    = (const float*)d_in[0];
  const float* ea   = (const float*)d_in[1];
  const int*   ei   = (const int*)d_in[2];
  const float* eps1 = (const float*)d_in[4];
  const float* el1w = (const float*)d_in[5];
  const float* el1b = (const float*)d_in[6];
  const float* n1w1 = (const float*)d_in[7];
  const float* n1b1 = (const float*)d_in[8];
  const float* n1g  = (const float*)d_in[9];
  const float* n1bt = (const float*)d_in[10];
  const float* n1w2 = (const float*)d_in[11];
  const float* n1b2 = (const float*)d_in[12];
  const float* eps2 = (const float*)d_in[13];
  const float* el2w = (const float*)d_in[14];
  const float* el2b = (const float*)d_in[15];
  const float* n2w1 = (const float*)d_in[16];
  const float* n2b1 = (const float*)d_in[17];
  const float* n2g  = (const float*)d_in[18];
  const float* n2bt = (const float*)d_in[19];
  const float* n2w2 = (const float*)d_in[20];
  const float* n2b2 = (const float*)d_in[21];
  const float* regw = (const float*)d_in[22];
  const float* regb = (const float*)d_in[23];
  const float* endw = (const float*)d_in[24];
  const float* endb = (const float*)d_in[25];
  const int* srcp = ei;
  const int* dstp = ei + NE;

  // ---- tier-A layout (floats) ----
  const size_t o_stats  = 0;         // 512 floats
  const size_t o_rowptr = 512;       // NN+1 ints
  const size_t o_cnt    = 100516;    // NN ints (scatter offsets)
  const size_t o_buf0   = 200576;    // N*64 floats; doubles as msg1 [E,2] pre-layer-2
  const size_t o_buf1   = 6600576;   // N*64 floats
  const size_t o_agg1   = 13000576;  // N*2 floats
  const size_t o_edat   = 13200576;  // packed: E*8 floats | slim: E ints
  const size_t needA2 = (o_edat + (size_t)NE * 8) * 4;  // ~155.2 MB
  const size_t needA1 = (o_edat + (size_t)NE) * 4;      // ~65.6 MB
  const size_t needB  = (2 * 6600000 + 384) * 4;        // ~52.8 MB

  float* wsf = (float*)d_ws;

  if (ws_size >= needA1) {
    const bool packed = ws_size >= needA2;
    float* stats = wsf + o_stats;
    int* rowptr  = (int*)(wsf + o_rowptr);
    int* cnt     = (int*)(wsf + o_cnt);
    float* buf0  = wsf + o_buf0;
    float* buf1  = wsf + o_buf1;
    float* agg1  = wsf + o_agg1;
    float* edat  = wsf + o_edat;
    float* msg1  = buf0;  // [E,2] == N*64 floats exactly; free until layer 2

    // ---- CSR build (once, shared by all 3 layers) ----
    hipMemsetAsync(cnt, 0, NN * sizeof(int), stream);
    count_kernel<<<4096, 256, 0, stream>>>(dstp, cnt);
    scan_kernel<<<1, 1024, 0, stream>>>(cnt, rowptr, cnt);
    if (packed)
      scatter2p_kernel<<<4096, 256, 0, stream>>>(srcp, dstp, ea, cnt, edat,
                                                 x, el1w, el1b, msg1);
    else
      scatter1_kernel<<<4096, 256, 0, stream>>>(dstp, cnt, (int*)edat);

    // ---- layer 1 ----
    hipMemsetAsync(stats, 0, 128 * sizeof(double), stream);
    if (packed)
      l1sum_kernel<<<391, 256, 0, stream>>>(rowptr, msg1, agg1);
    else
      l1agg_kernel<<<391, 256, 0, stream>>>(rowptr, (const int*)edat, srcp, ea,
                                            x, el1w, el1b, agg1);
    nodeA2_kernel<<<2048, 256, 0, stream>>>(x, agg1, buf1, n1w1, n1b1, eps1, stats);
    statsfin_kernel<<<1, 64, 0, stream>>>(stats, n1g, n1bt);
    nodeB_kernel<<<2048, 256, 0, stream>>>(buf1, buf1, n1w2, n1b2, stats);

    // ---- layers 2,3 (shared weights) ----
    float* cur = buf1;
    float* wrk = buf0;
    for (int l = 0; l < 2; l++) {
      hipMemsetAsync(stats, 0, 128 * sizeof(double), stream);
      if (packed)
        gine64p_kernel<<<4096, 256, 0, stream>>>(rowptr, edat, cur, el2w, el2b,
                                                 n2w1, n2b1, eps2, wrk, stats);
      else
        gine64s_kernel<<<4096, 256, 0, stream>>>(rowptr, (const int*)edat, srcp,
                                                 ea, cur, el2w, el2b, n2w1, n2b1,
                                                 eps2, wrk, stats);
      statsfin_kernel<<<1, 64, 0, stream>>>(stats, n2g, n2bt);
      nodeB_kernel<<<2048, 256, 0, stream>>>(wrk, wrk, n2w2, n2b2, stats);
      float* tmp = cur; cur = wrk; wrk = tmp;
    }

    final_kernel<<<(NN + 255) / 256, 256, 0, stream>>>(cur, regw, regb, endw, endb,
                                                       (float*)d_out);
    return;
  }

  // ================= fallback tier B (round-1 proven path) =================
  if (ws_size < needB) return;
  const size_t BUF = 6600000;
  float* buf0 = (float*)d_ws;
  float* buf1 = buf0 + BUF;
  float* stats = buf1 + BUF;

  float* t1 = buf1;
  float* agg1 = buf1 + NN * 64;
  hipMemsetAsync(agg1, 0, NN * 2 * sizeof(float), stream);
  hipMemsetAsync(stats, 0, 128 * sizeof(double), stream);
  edge1_kernel<<<2048, 256, 0, stream>>>(x, ea, srcp, dstp, el1w, el1b, agg1);
  nodeA2_kernel<<<2048, 256, 0, stream>>>(x, agg1, t1, n1w1, n1b1, eps1, stats);
  statsfin_kernel<<<1, 64, 0, stream>>>(stats, n1g, n1bt);
  nodeB_kernel<<<2048, 256, 0, stream>>>(t1, buf1, n1w2, n1b2, stats);

  float* cur = buf1;
  float* wrk = buf0;
  for (int l = 0; l < 2; l++) {
    hipMemsetAsync(wrk, 0, NN * 64 * sizeof(float), stream);
    hipMemsetAsync(stats, 0, 128 * sizeof(double), stream);
    edge64_kernel<<<2048, 256, 0, stream>>>(cur, ea, srcp, dstp, el2w, el2b, wrk);
    nodeA64_kernel<<<2048, 256, 0, stream>>>(cur, wrk, n2w1, n2b1, eps2, stats);
    statsfin_kernel<<<1, 64, 0, stream>>>(stats, n2g, n2bt);
    nodeB_kernel<<<2048, 256, 0, stream>>>(wrk, wrk, n2w2, n2b2, stats);
    float* tmp = cur; cur = wrk; wrk = tmp;
  }

  final_kernel<<<(NN + 255) / 256, 256, 0, stream>>>(cur, regw, regb, endw, endb,
                                                     (float*)d_out);
}